// Round 3
// baseline (605.835 us; speedup 1.0000x reference)
//
#include <hip/hip_runtime.h>
#include <hip/hip_bf16.h>

#define S_LEN 2048
#define HID   2048
#define NH    16
#define NKV   4
#define HD    128
#define KVD   512            // NKV*HD
#define SCALE2 0.0078125f    // (D^-0.5)^2 = 1/128

typedef __bf16 bf16;
typedef __attribute__((ext_vector_type(8))) __bf16 bf16x8;
typedef __attribute__((ext_vector_type(4))) float f32x4;

// ---- 8-element loaders: global (f32 or bf16) -> bf16x8 --------------------
__device__ inline bf16x8 load8(const bf16* p) { return *(const bf16x8*)p; }
__device__ inline bf16x8 load8(const float* p) {
    const float4* q = (const float4*)p;
    float4 a = q[0], b = q[1];
    bf16x8 r;
    r[0] = (bf16)a.x; r[1] = (bf16)a.y; r[2] = (bf16)a.z; r[3] = (bf16)a.w;
    r[4] = (bf16)b.x; r[5] = (bf16)b.y; r[6] = (bf16)b.z; r[7] = (bf16)b.w;
    return r;
}

// ---------------------------------------------------------------------------
// GEMM: C[M,N] = A[M,K] @ B[K,N], row-major. A/B may be f32 (lowered to bf16
// in staging) or bf16. 64x64 tile, 4 waves, 16x64 slab/wave, BK=32.
// m92-verified MFMA pattern; C/D layout row=quad*4+r, col=l16.
// ---------------------------------------------------------------------------
template<typename TA, typename TB, typename TC>
__global__ __launch_bounds__(256) void gemm_kernel(const TA* __restrict__ A,
                                                   const TB* __restrict__ B,
                                                   TC* __restrict__ C,
                                                   int M, int N, int K)
{
    __shared__ __attribute__((aligned(16))) bf16 As[64][40];   // [m][k]
    __shared__ __attribute__((aligned(16))) bf16 Bs[64][40];   // [n][k] (transposed)
    const int tid  = threadIdx.x;
    const int w    = tid >> 6, lane = tid & 63;
    const int l16  = lane & 15, quad = lane >> 4;
    const int mb   = blockIdx.x * 64, nb = blockIdx.y * 64;

    f32x4 acc[4] = {};

    const int arow = tid >> 2, acol = (tid & 3) * 8;  // A staging: 8 elems/thread
    const int bk   = tid >> 3, bn   = (tid & 7) * 8;  // B staging: 8 elems, scatter

    for (int kt = 0; kt < K; kt += 32) {
        __syncthreads();
        *(bf16x8*)&As[arow][acol] = load8(&A[(size_t)(mb + arow) * K + kt + acol]);
        bf16x8 bv = load8(&B[(size_t)(kt + bk) * N + nb + bn]);
        #pragma unroll
        for (int x = 0; x < 8; ++x) Bs[bn + x][bk] = bv[x];
        __syncthreads();

        bf16x8 af = *(const bf16x8*)&As[w * 16 + l16][quad * 8];
        #pragma unroll
        for (int t = 0; t < 4; ++t) {
            bf16x8 bfr = *(const bf16x8*)&Bs[t * 16 + l16][quad * 8];
            acc[t] = __builtin_amdgcn_mfma_f32_16x16x32_bf16(af, bfr, acc[t], 0, 0, 0);
        }
    }
    #pragma unroll
    for (int t = 0; t < 4; ++t)
        #pragma unroll
        for (int r = 0; r < 4; ++r)
            C[(size_t)(mb + w * 16 + quad * 4 + r) * N + nb + t * 16 + l16] =
                (TC)acc[t][r];
}

// ---------------------------------------------------------------------------
// In-place RoPE on bf16 buffer; cos/sin are f32. Thread owns pair (d, d+64).
// ---------------------------------------------------------------------------
template<int HEADS>
__global__ __launch_bounds__(256) void rope_kernel(bf16* __restrict__ x,
                                                   const float* __restrict__ cosb,
                                                   const float* __restrict__ sinb)
{
    int idx = blockIdx.x * 256 + threadIdx.x;
    int s   = idx / (HEADS * 64);
    int rem = idx % (HEADS * 64);
    int h   = rem >> 6, d = rem & 63;
    size_t base = (size_t)s * (HEADS * 128) + h * 128 + d;
    float x0 = (float)x[base], x1 = (float)x[base + 64];
    float c0 = cosb[s * 128 + d], c1 = cosb[s * 128 + d + 64];
    float n0 = sinb[s * 128 + d], n1 = sinb[s * 128 + d + 64];
    x[base]      = (bf16)(x0 * c0 - x1 * n0);
    x[base + 64] = (bf16)(x1 * c1 + x0 * n1);
}

// ---------------------------------------------------------------------------
// Gate projection (full f32): graw[c][s] = log_sigmoid(hs[s,:] . Wg[:,c]).
// One wave per sequence position.
// ---------------------------------------------------------------------------
__global__ __launch_bounds__(64) void gproj_kernel(const float* __restrict__ hs,
                                                   const float* __restrict__ Wg,
                                                   float* __restrict__ graw)
{
    int s = blockIdx.x, lane = threadIdx.x;
    float a0 = 0.f, a1 = 0.f, a2 = 0.f, a3 = 0.f;
    for (int kk = lane; kk < HID; kk += 64) {
        float h = hs[(size_t)s * HID + kk];
        const float* wr = &Wg[kk * 4];
        a0 += h * wr[0]; a1 += h * wr[1];
        a2 += h * wr[2]; a3 += h * wr[3];
    }
    #pragma unroll
    for (int off = 32; off >= 1; off >>= 1) {
        a0 += __shfl_xor(a0, off); a1 += __shfl_xor(a1, off);
        a2 += __shfl_xor(a2, off); a3 += __shfl_xor(a3, off);
    }
    if (lane == 0) {
        float vv[4] = {a0, a1, a2, a3};
        #pragma unroll
        for (int c = 0; c < 4; ++c) {
            float x = vv[c];
            graw[c * S_LEN + s] = fminf(x, 0.f) - log1pf(expf(-fabsf(x)));  // log_sigmoid
        }
    }
}

// ---------------------------------------------------------------------------
// Inclusive cumsum over s per kv head. One block per head, Hillis-Steele.
// ---------------------------------------------------------------------------
__global__ __launch_bounds__(256) void cumsum_kernel(const float* __restrict__ graw,
                                                     float* __restrict__ G)
{
    int c = blockIdx.x, t = threadIdx.x;
    __shared__ float sums[256];
    float loc[8];
    float run = 0.f;
    #pragma unroll
    for (int i = 0; i < 8; ++i) { run += graw[c * S_LEN + t * 8 + i]; loc[i] = run; }
    sums[t] = run;
    __syncthreads();
    for (int off = 1; off < 256; off <<= 1) {
        float add = (t >= off) ? sums[t - off] : 0.f;
        __syncthreads();
        sums[t] += add;
        __syncthreads();
    }
    float offset = sums[t] - run;   // exclusive prefix of this thread's chunk
    #pragma unroll
    for (int i = 0; i < 8; ++i) G[c * S_LEN + t * 8 + i] = offset + loc[i];
}

// ---------------------------------------------------------------------------
// Causal decay attention. Block = (64-query tile, head). 4 waves x 16 q-rows.
// scores = (q.k*SCALE)^2 * exp(G_i-G_j), j<=i; out = scores@V / max(sum,1)
// ---------------------------------------------------------------------------
__global__ __launch_bounds__(256) void attn_kernel(const bf16* __restrict__ q,
                                                   const bf16* __restrict__ k,
                                                   const bf16* __restrict__ v,
                                                   const float* __restrict__ G,
                                                   bf16* __restrict__ out)
{
    const int qt = blockIdx.x, h = blockIdx.y, kvh = h >> 2;
    const int qb = qt * 64;
    const int tid = threadIdx.x, w = tid >> 6, lane = tid & 63;
    const int l16 = lane & 15, quad = lane >> 4;

    __shared__ __attribute__((aligned(16))) bf16 Ks[64][136];     // [j][d]
    __shared__ __attribute__((aligned(16))) bf16 Vt[128][72];     // [d][j]
    __shared__ __attribute__((aligned(16))) bf16 Sb[4][16][72];   // per-wave S [i][j]

    // q fragments (A-operand: m=l16, k=quad*8+x)
    bf16x8 qf[4];
    const int qrow = qb + w * 16 + l16;
    #pragma unroll
    for (int kc = 0; kc < 4; ++kc)
        qf[kc] = *(const bf16x8*)&q[(size_t)qrow * HID + h * HD + kc * 32 + quad * 8];

    const int irow = qb + w * 16 + quad * 4;   // C-layout row base
    float Gq[4];
    #pragma unroll
    for (int r = 0; r < 4; ++r) Gq[r] = G[kvh * S_LEN + irow + r];

    f32x4 acco[8] = {};
    float den[4] = {0.f, 0.f, 0.f, 0.f};

    for (int kt = 0; kt <= qt; ++kt) {
        const int jb = kt * 64;
        __syncthreads();   // protect Ks/Vt from previous iteration's readers
        #pragma unroll
        for (int it = 0; it < 4; ++it) {
            int cid = tid + it * 256;
            int row = cid >> 4, cc = (cid & 15) * 8;
            *(int4*)&Ks[row][cc] = *(const int4*)&k[(size_t)(jb + row) * KVD + kvh * HD + cc];
            bf16x8 vv = *(const bf16x8*)&v[(size_t)(jb + row) * KVD + kvh * HD + cc];
            #pragma unroll
            for (int x = 0; x < 8; ++x) Vt[cc + x][row] = vv[x];
        }
        __syncthreads();

        // S = q @ K^T
        f32x4 accs[4] = {};
        #pragma unroll
        for (int t = 0; t < 4; ++t)
            #pragma unroll
            for (int kc = 0; kc < 4; ++kc) {
                bf16x8 bfr = *(const bf16x8*)&Ks[t * 16 + l16][kc * 32 + quad * 8];
                accs[t] = __builtin_amdgcn_mfma_f32_16x16x32_bf16(qf[kc], bfr, accs[t], 0, 0, 0);
            }

        // mask + decay + scale; accumulate den; stage S via LDS into A-layout
        #pragma unroll
        for (int t = 0; t < 4; ++t) {
            int j = jb + t * 16 + l16;
            float Gj = G[kvh * S_LEN + j];
            #pragma unroll
            for (int r = 0; r < 4; ++r) {
                float sc = 0.f;
                if (j <= irow + r) {
                    float d0 = accs[t][r];
                    float e = __expf(fminf(Gq[r] - Gj, 0.f));   // decay <= 1
                    sc = fminf(d0 * d0 * SCALE2 * e, 3.0e34f);
                }
                den[r] += sc;
                Sb[w][quad * 4 + r][t * 16 + l16] = (bf16)sc;
            }
        }
        __syncthreads();   // drain Sb writes before A-frag reads

        // O += S @ V
        #pragma unroll
        for (int kk = 0; kk < 2; ++kk) {
            bf16x8 af = *(const bf16x8*)&Sb[w][l16][kk * 32 + quad * 8];
            #pragma unroll
            for (int dt = 0; dt < 8; ++dt) {
                bf16x8 bfr = *(const bf16x8*)&Vt[dt * 16 + l16][kk * 32 + quad * 8];
                acco[dt] = __builtin_amdgcn_mfma_f32_16x16x32_bf16(af, bfr, acco[dt], 0, 0, 0);
            }
        }
    }

    // reduce den across the 16 j-lanes
    #pragma unroll
    for (int r = 0; r < 4; ++r) {
        #pragma unroll
        for (int off = 1; off < 16; off <<= 1) den[r] += __shfl_xor(den[r], off);
        den[r] = 1.f / fmaxf(den[r], 1.f);
    }
    #pragma unroll
    for (int dt = 0; dt < 8; ++dt)
        #pragma unroll
        for (int r = 0; r < 4; ++r)
            out[(size_t)(irow + r) * HID + h * HD + dt * 16 + l16] = (bf16)(acco[dt][r] * den[r]);
}

// ---------------------------------------------------------------------------
extern "C" void kernel_launch(void* const* d_in, const int* in_sizes, int n_in,
                              void* d_out, int out_size, void* d_ws, size_t ws_size,
                              hipStream_t stream)
{
    const float* hs   = (const float*)d_in[0];
    const float* cosb = (const float*)d_in[1];
    const float* sinb = (const float*)d_in[2];
    const float* Wq   = (const float*)d_in[3];
    const float* Wk   = (const float*)d_in[4];
    const float* Wv   = (const float*)d_in[5];
    const float* Wg   = (const float*)d_in[6];
    const float* Wo   = (const float*)d_in[7];
    float* out = (float*)d_out;

    char* p = (char*)d_ws;
    bf16*  qbuf = (bf16*)p;  p += (size_t)S_LEN * HID * 2;   // 8 MB
    bf16*  kbuf = (bf16*)p;  p += (size_t)S_LEN * KVD * 2;   // 2 MB
    bf16*  vbuf = (bf16*)p;  p += (size_t)S_LEN * KVD * 2;   // 2 MB
    float* graw = (float*)p; p += (size_t)NKV * S_LEN * 4;   // 32 KB
    float* G    = (float*)p; p += (size_t)NKV * S_LEN * 4;   // 32 KB
    bf16*  abuf = (bf16*)p;  p += (size_t)S_LEN * HID * 2;   // 8 MB

    gemm_kernel<float, float, bf16><<<dim3(32, 32), 256, 0, stream>>>(hs, Wq, qbuf, S_LEN, HID, HID);
    gemm_kernel<float, float, bf16><<<dim3(32,  8), 256, 0, stream>>>(hs, Wk, kbuf, S_LEN, KVD, HID);
    gemm_kernel<float, float, bf16><<<dim3(32,  8), 256, 0, stream>>>(hs, Wv, vbuf, S_LEN, KVD, HID);
    gproj_kernel<<<S_LEN, 64, 0, stream>>>(hs, Wg, graw);
    cumsum_kernel<<<NKV, 256, 0, stream>>>(graw, G);
    rope_kernel<NH><<<(S_LEN * NH * 64) / 256, 256, 0, stream>>>(qbuf, cosb, sinb);
    rope_kernel<NKV><<<(S_LEN * NKV * 64) / 256, 256, 0, stream>>>(kbuf, cosb, sinb);
    attn_kernel<<<dim3(32, NH), 256, 0, stream>>>(qbuf, kbuf, vbuf, G, abuf);
    gemm_kernel<bf16, float, float><<<dim3(32, 32), 256, 0, stream>>>(abuf, Wo, out, S_LEN, HID, HID);
}

// Round 4
// 406.187 us; speedup vs baseline: 1.4915x; 1.4915x over previous
//
#include <hip/hip_runtime.h>
#include <hip/hip_bf16.h>

#define S_LEN 2048
#define HID   2048
#define NH    16
#define NKV   4
#define HD    128
#define KVD   512            // NKV*HD
#define SCALE2 0.0078125f    // (D^-0.5)^2 = 1/128

typedef __bf16 bf16;
typedef __attribute__((ext_vector_type(8))) __bf16 bf16x8;
typedef __attribute__((ext_vector_type(4))) float f32x4;

// async global->LDS, 16B per lane; LDS dest must be wave-uniform base (+lane*16)
__device__ __forceinline__ void gload_lds16(const bf16* g, bf16* l) {
    __builtin_amdgcn_global_load_lds((const __attribute__((address_space(1))) void*)g,
                                     (__attribute__((address_space(3))) void*)l, 16, 0, 0);
}

// ---------------------------------------------------------------------------
// f32 -> bf16 convert (vectorized, 8 elems/thread)
// ---------------------------------------------------------------------------
__global__ __launch_bounds__(256) void cvt_kernel(const float* __restrict__ in,
                                                  bf16* __restrict__ out, int n)
{
    int i = (blockIdx.x * 256 + threadIdx.x) * 8;
    if (i >= n) return;
    const float4* q = (const float4*)&in[i];
    float4 a = q[0], b = q[1];
    bf16x8 r;
    r[0]=(bf16)a.x; r[1]=(bf16)a.y; r[2]=(bf16)a.z; r[3]=(bf16)a.w;
    r[4]=(bf16)b.x; r[5]=(bf16)b.y; r[6]=(bf16)b.z; r[7]=(bf16)b.w;
    *(bf16x8*)&out[i] = r;
}

// ---------------------------------------------------------------------------
// W[K][N] f32 -> Wt[N][K] bf16, 64x64 LDS tile (pad 65: conflict-free).
// ---------------------------------------------------------------------------
__global__ __launch_bounds__(256) void transpose_cvt_kernel(const float* __restrict__ W,
                                                            bf16* __restrict__ Wt,
                                                            int K, int N)
{
    __shared__ float Ts[64][65];
    const int kb = blockIdx.x * 64, nb = blockIdx.y * 64;
    const int t = threadIdx.x;
    const int tr = t >> 6, tc = t & 63;
    #pragma unroll
    for (int p = 0; p < 16; ++p) {
        int k = p * 4 + tr;
        Ts[k][tc] = W[(size_t)(kb + k) * N + nb + tc];
    }
    __syncthreads();
    const int nr = t >> 3, kc = t & 7;
    #pragma unroll
    for (int p = 0; p < 2; ++p) {
        int n = p * 32 + nr;
        bf16x8 o;
        #pragma unroll
        for (int x = 0; x < 8; ++x) o[x] = (bf16)Ts[kc * 8 + x][n];
        *(bf16x8*)&Wt[(size_t)(nb + n) * K + kb + kc * 8] = o;
    }
}

// ---------------------------------------------------------------------------
// m97-style GEMM: C[M,N] = A[M,K] @ Bt[N,K]^T, bf16 in, TC out.
// 128x128 tile, BK=32, 4 waves, 4x4 16x16 MFMA grid per wave,
// global_load_lds width-16 staging (no LDS padding — required by wave-uniform
// base + lane*16 semantics; fragment reads are conflict-free at stride 64B).
// TRANS_OUT: write C^T (col-major) instead.
// ---------------------------------------------------------------------------
template<typename TC, bool TRANS_OUT>
__global__ __launch_bounds__(256) void gemm128_kernel(const bf16* __restrict__ A,
                                                      const bf16* __restrict__ Bt,
                                                      TC* __restrict__ C,
                                                      int M, int N, int K)
{
    __shared__ __attribute__((aligned(16))) bf16 As[128][32];
    __shared__ __attribute__((aligned(16))) bf16 Bs[128][32];
    const int tid = threadIdx.x, w = tid >> 6, lane = tid & 63;
    const int l16 = lane & 15, quad = lane >> 4;
    const int mb = blockIdx.x * 128, nb = blockIdx.y * 128;
    const int m0 = (w & 1) * 64, n0 = (w >> 1) * 64;
    const int srow = lane >> 2, scol = (lane & 3) * 8;   // 16 rows x 32B per chunk

    f32x4 acc[4][4] = {};

    for (int kt = 0; kt < K; kt += 32) {
        __syncthreads();
        // wave w stages rows [32w, 32w+32) of both tiles: 4 async 1KB chunks
        gload_lds16(&A [(size_t)(mb + w * 32 +      srow) * K + kt + scol], &As[w * 32     ][0]);
        gload_lds16(&A [(size_t)(mb + w * 32 + 16 + srow) * K + kt + scol], &As[w * 32 + 16][0]);
        gload_lds16(&Bt[(size_t)(nb + w * 32 +      srow) * K + kt + scol], &Bs[w * 32     ][0]);
        gload_lds16(&Bt[(size_t)(nb + w * 32 + 16 + srow) * K + kt + scol], &Bs[w * 32 + 16][0]);
        __syncthreads();

        bf16x8 af[4], bfr[4];
        #pragma unroll
        for (int t = 0; t < 4; ++t) af[t]  = *(const bf16x8*)&As[m0 + t * 16 + l16][quad * 8];
        #pragma unroll
        for (int u = 0; u < 4; ++u) bfr[u] = *(const bf16x8*)&Bs[n0 + u * 16 + l16][quad * 8];
        #pragma unroll
        for (int t = 0; t < 4; ++t)
            #pragma unroll
            for (int u = 0; u < 4; ++u)
                acc[t][u] = __builtin_amdgcn_mfma_f32_16x16x32_bf16(af[t], bfr[u], acc[t][u], 0, 0, 0);
    }

    #pragma unroll
    for (int t = 0; t < 4; ++t)
        #pragma unroll
        for (int u = 0; u < 4; ++u)
            #pragma unroll
            for (int r = 0; r < 4; ++r) {
                int row = mb + m0 + t * 16 + quad * 4 + r;
                int col = nb + n0 + u * 16 + l16;
                if (TRANS_OUT) C[(size_t)col * M + row] = (TC)acc[t][u][r];
                else           C[(size_t)row * N + col] = (TC)acc[t][u][r];
            }
}

// ---------------------------------------------------------------------------
// In-place RoPE on bf16 buffer; cos/sin f32. Thread owns pair (d, d+64).
// ---------------------------------------------------------------------------
template<int HEADS>
__global__ __launch_bounds__(256) void rope_kernel(bf16* __restrict__ x,
                                                   const float* __restrict__ cosb,
                                                   const float* __restrict__ sinb)
{
    int idx = blockIdx.x * 256 + threadIdx.x;
    int s   = idx / (HEADS * 64);
    int rem = idx % (HEADS * 64);
    int h   = rem >> 6, d = rem & 63;
    size_t base = (size_t)s * (HEADS * 128) + h * 128 + d;
    float x0 = (float)x[base], x1 = (float)x[base + 64];
    float c0 = cosb[s * 128 + d], c1 = cosb[s * 128 + d + 64];
    float n0 = sinb[s * 128 + d], n1 = sinb[s * 128 + d + 64];
    x[base]      = (bf16)(x0 * c0 - x1 * n0);
    x[base + 64] = (bf16)(x1 * c1 + x0 * n1);
}

// ---------------------------------------------------------------------------
// Gate projection (full f32): graw[c][s] = log_sigmoid(hs[s,:] . Wg[:,c]).
// ---------------------------------------------------------------------------
__global__ __launch_bounds__(64) void gproj_kernel(const float* __restrict__ hs,
                                                   const float* __restrict__ Wg,
                                                   float* __restrict__ graw)
{
    int s = blockIdx.x, lane = threadIdx.x;
    float a0 = 0.f, a1 = 0.f, a2 = 0.f, a3 = 0.f;
    for (int kk = lane; kk < HID; kk += 64) {
        float h = hs[(size_t)s * HID + kk];
        const float* wr = &Wg[kk * 4];
        a0 += h * wr[0]; a1 += h * wr[1];
        a2 += h * wr[2]; a3 += h * wr[3];
    }
    #pragma unroll
    for (int off = 32; off >= 1; off >>= 1) {
        a0 += __shfl_xor(a0, off); a1 += __shfl_xor(a1, off);
        a2 += __shfl_xor(a2, off); a3 += __shfl_xor(a3, off);
    }
    if (lane == 0) {
        float vv[4] = {a0, a1, a2, a3};
        #pragma unroll
        for (int c = 0; c < 4; ++c) {
            float x = vv[c];
            graw[c * S_LEN + s] = fminf(x, 0.f) - log1pf(expf(-fabsf(x)));
        }
    }
}

// ---------------------------------------------------------------------------
// Inclusive cumsum over s per kv head.
// ---------------------------------------------------------------------------
__global__ __launch_bounds__(256) void cumsum_kernel(const float* __restrict__ graw,
                                                     float* __restrict__ G)
{
    int c = blockIdx.x, t = threadIdx.x;
    __shared__ float sums[256];
    float loc[8];
    float run = 0.f;
    #pragma unroll
    for (int i = 0; i < 8; ++i) { run += graw[c * S_LEN + t * 8 + i]; loc[i] = run; }
    sums[t] = run;
    __syncthreads();
    for (int off = 1; off < 256; off <<= 1) {
        float add = (t >= off) ? sums[t - off] : 0.f;
        __syncthreads();
        sums[t] += add;
        __syncthreads();
    }
    float offset = sums[t] - run;
    #pragma unroll
    for (int i = 0; i < 8; ++i) G[c * S_LEN + t * 8 + i] = offset + loc[i];
}

// ---------------------------------------------------------------------------
// Causal decay attention. Block = (64-query tile, head), qt reversed for
// tail balance. V consumed pre-transposed (vT[kvh*128+d][s]) -> pure b128
// staging, zero bank conflicts. 2 barriers/iter (Sb is wave-private).
// ---------------------------------------------------------------------------
__global__ __launch_bounds__(256) void attn_kernel(const bf16* __restrict__ q,
                                                   const bf16* __restrict__ k,
                                                   const bf16* __restrict__ vT,
                                                   const float* __restrict__ G,
                                                   bf16* __restrict__ out)
{
    const int qt = gridDim.x - 1 - blockIdx.x;       // long blocks first
    const int h = blockIdx.y, kvh = h >> 2;
    const int qb = qt * 64;
    const int tid = threadIdx.x, w = tid >> 6, lane = tid & 63;
    const int l16 = lane & 15, quad = lane >> 4;

    __shared__ __attribute__((aligned(16))) bf16 Ks[64][136];     // [j][d]
    __shared__ __attribute__((aligned(16))) bf16 Vt[128][72];     // [d][j]
    __shared__ __attribute__((aligned(16))) bf16 Sb[4][16][72];   // per-wave S [i][j]

    bf16x8 qf[4];
    const int qrow = qb + w * 16 + l16;
    #pragma unroll
    for (int kc = 0; kc < 4; ++kc)
        qf[kc] = *(const bf16x8*)&q[(size_t)qrow * HID + h * HD + kc * 32 + quad * 8];

    const int irow = qb + w * 16 + quad * 4;
    float Gq[4];
    #pragma unroll
    for (int r = 0; r < 4; ++r) Gq[r] = G[kvh * S_LEN + irow + r];

    f32x4 acco[8] = {};
    float den[4] = {0.f, 0.f, 0.f, 0.f};

    for (int kt = 0; kt <= qt; ++kt) {
        const int jb = kt * 64;
        __syncthreads();
        #pragma unroll
        for (int it = 0; it < 4; ++it) {            // K tile: b128 row-major
            int cid = tid + it * 256;
            int row = cid >> 4, cc = (cid & 15) * 8;
            *(int4*)&Ks[row][cc] = *(const int4*)&k[(size_t)(jb + row) * KVD + kvh * HD + cc];
        }
        #pragma unroll
        for (int it = 0; it < 4; ++it) {            // V tile: b128 from vT
            int d = (tid >> 3) + it * 32;
            int jc = (tid & 7) * 8;
            *(int4*)&Vt[d][jc] = *(const int4*)&vT[((size_t)kvh * HD + d) * S_LEN + jb + jc];
        }
        __syncthreads();

        // S = q @ K^T
        f32x4 accs[4] = {};
        #pragma unroll
        for (int t = 0; t < 4; ++t)
            #pragma unroll
            for (int kc = 0; kc < 4; ++kc) {
                bf16x8 bfr = *(const bf16x8*)&Ks[t * 16 + l16][kc * 32 + quad * 8];
                accs[t] = __builtin_amdgcn_mfma_f32_16x16x32_bf16(qf[kc], bfr, accs[t], 0, 0, 0);
            }

        // mask + decay + scale; den; stage S into wave-private A-layout tile
        #pragma unroll
        for (int t = 0; t < 4; ++t) {
            int j = jb + t * 16 + l16;
            float Gj = G[kvh * S_LEN + j];
            #pragma unroll
            for (int r = 0; r < 4; ++r) {
                float sc = 0.f;
                if (j <= irow + r) {
                    float d0 = accs[t][r];
                    float e = __expf(fminf(Gq[r] - Gj, 0.f));
                    sc = fminf(d0 * d0 * SCALE2 * e, 3.0e34f);
                }
                den[r] += sc;
                Sb[w][quad * 4 + r][t * 16 + l16] = (bf16)sc;
            }
        }
        // no barrier: Sb[w] written & read by the same wave (lgkmcnt ordering)

        // O += S @ V
        #pragma unroll
        for (int kk = 0; kk < 2; ++kk) {
            bf16x8 af = *(const bf16x8*)&Sb[w][l16][kk * 32 + quad * 8];
            #pragma unroll
            for (int dt = 0; dt < 8; ++dt) {
                bf16x8 bfr = *(const bf16x8*)&Vt[dt * 16 + l16][kk * 32 + quad * 8];
                acco[dt] = __builtin_amdgcn_mfma_f32_16x16x32_bf16(af, bfr, acco[dt], 0, 0, 0);
            }
        }
    }

    #pragma unroll
    for (int r = 0; r < 4; ++r) {
        #pragma unroll
        for (int off = 1; off < 16; off <<= 1) den[r] += __shfl_xor(den[r], off);
        den[r] = 1.f / fmaxf(den[r], 1.f);
    }
    #pragma unroll
    for (int dt = 0; dt < 8; ++dt)
        #pragma unroll
        for (int r = 0; r < 4; ++r)
            out[(size_t)(irow + r) * HID + h * HD + dt * 16 + l16] = (bf16)(acco[dt][r] * den[r]);
}

// ---------------------------------------------------------------------------
extern "C" void kernel_launch(void* const* d_in, const int* in_sizes, int n_in,
                              void* d_out, int out_size, void* d_ws, size_t ws_size,
                              hipStream_t stream)
{
    const float* hs   = (const float*)d_in[0];
    const float* cosb = (const float*)d_in[1];
    const float* sinb = (const float*)d_in[2];
    const float* Wq   = (const float*)d_in[3];
    const float* Wk   = (const float*)d_in[4];
    const float* Wv   = (const float*)d_in[5];
    const float* Wg   = (const float*)d_in[6];
    const float* Wo   = (const float*)d_in[7];
    float* out = (float*)d_out;

    char* p = (char*)d_ws;
    bf16*  qbuf = (bf16*)p;  p += (size_t)S_LEN * HID * 2;   // 8 MB
    bf16*  kbuf = (bf16*)p;  p += (size_t)S_LEN * KVD * 2;   // 2 MB
    bf16*  vT   = (bf16*)p;  p += (size_t)S_LEN * KVD * 2;   // 2 MB (transposed [KVD][S])
    bf16*  abuf = (bf16*)p;  p += (size_t)S_LEN * HID * 2;   // 8 MB
    bf16*  hsb  = (bf16*)p;  p += (size_t)S_LEN * HID * 2;   // 8 MB
    bf16*  WqT  = (bf16*)p;  p += (size_t)HID * HID * 2;     // 8 MB
    bf16*  WkT  = (bf16*)p;  p += (size_t)HID * KVD * 2;     // 2 MB
    bf16*  WvT  = (bf16*)p;  p += (size_t)HID * KVD * 2;     // 2 MB
    bf16*  WoT  = (bf16*)p;  p += (size_t)HID * HID * 2;     // 8 MB
    float* graw = (float*)p; p += (size_t)NKV * S_LEN * 4;
    float* G    = (float*)p; p += (size_t)NKV * S_LEN * 4;

    // pre-pass: bf16 convert + weight transposes
    cvt_kernel<<<(S_LEN * HID) / (256 * 8), 256, 0, stream>>>(hs, hsb, S_LEN * HID);
    transpose_cvt_kernel<<<dim3(32, 32), 256, 0, stream>>>(Wq, WqT, HID, HID);
    transpose_cvt_kernel<<<dim3(32,  8), 256, 0, stream>>>(Wk, WkT, HID, KVD);
    transpose_cvt_kernel<<<dim3(32,  8), 256, 0, stream>>>(Wv, WvT, HID, KVD);
    transpose_cvt_kernel<<<dim3(32, 32), 256, 0, stream>>>(Wo, WoT, HID, HID);

    // projections (V written transposed for conflict-free attention staging)
    gemm128_kernel<bf16,  false><<<dim3(16, 16), 256, 0, stream>>>(hsb, WqT, qbuf, S_LEN, HID, HID);
    gemm128_kernel<bf16,  false><<<dim3(16,  4), 256, 0, stream>>>(hsb, WkT, kbuf, S_LEN, KVD, HID);
    gemm128_kernel<bf16,  true ><<<dim3(16,  4), 256, 0, stream>>>(hsb, WvT, vT,   S_LEN, KVD, HID);

    gproj_kernel<<<S_LEN, 64, 0, stream>>>(hs, Wg, graw);
    cumsum_kernel<<<NKV, 256, 0, stream>>>(graw, G);
    rope_kernel<NH ><<<(S_LEN * NH  * 64) / 256, 256, 0, stream>>>(qbuf, cosb, sinb);
    rope_kernel<NKV><<<(S_LEN * NKV * 64) / 256, 256, 0, stream>>>(kbuf, cosb, sinb);

    attn_kernel<<<dim3(32, NH), 256, 0, stream>>>(qbuf, kbuf, vT, G, abuf);

    gemm128_kernel<float, false><<<dim3(16, 16), 256, 0, stream>>>(abuf, WoT, out, S_LEN, HID, HID);
}

// Round 5
// 312.342 us; speedup vs baseline: 1.9397x; 1.3005x over previous
//
#include <hip/hip_runtime.h>
#include <hip/hip_bf16.h>

#define S_LEN 2048
#define HID   2048
#define NH    16
#define NKV   4
#define HD    128
#define KVD   512            // NKV*HD
#define NQKV  3072           // HID + KVD + KVD
#define SCALE2 0.0078125f    // (D^-0.5)^2 = 1/128

typedef __bf16 bf16;
typedef __attribute__((ext_vector_type(8))) __bf16 bf16x8;
typedef __attribute__((ext_vector_type(4))) float f32x4;

// async global->LDS, 16B per lane; LDS dest is wave-uniform base + lane*16
__device__ __forceinline__ void gload_lds16(const bf16* g, bf16* l) {
    __builtin_amdgcn_global_load_lds((const __attribute__((address_space(1))) void*)g,
                                     (__attribute__((address_space(3))) void*)l, 16, 0, 0);
}

// ---------------------------------------------------------------------------
// f32 -> bf16 convert (vectorized, 8 elems/thread)
// ---------------------------------------------------------------------------
__global__ __launch_bounds__(256) void cvt_kernel(const float* __restrict__ in,
                                                  bf16* __restrict__ out, int n)
{
    int i = (blockIdx.x * 256 + threadIdx.x) * 8;
    if (i >= n) return;
    const float4* q = (const float4*)&in[i];
    float4 a = q[0], b = q[1];
    bf16x8 r;
    r[0]=(bf16)a.x; r[1]=(bf16)a.y; r[2]=(bf16)a.z; r[3]=(bf16)a.w;
    r[4]=(bf16)b.x; r[5]=(bf16)b.y; r[6]=(bf16)b.z; r[7]=(bf16)b.w;
    *(bf16x8*)&out[i] = r;
}

// ---------------------------------------------------------------------------
// W[K][N] f32 -> Wt[N][K] bf16, 64x64 LDS tile (pad 65: conflict-free).
// Wt may be a row-offset pointer into a concat buffer.
// ---------------------------------------------------------------------------
__global__ __launch_bounds__(256) void transpose_cvt_kernel(const float* __restrict__ W,
                                                            bf16* __restrict__ Wt,
                                                            int K, int N)
{
    __shared__ float Ts[64][65];
    const int kb = blockIdx.x * 64, nb = blockIdx.y * 64;
    const int t = threadIdx.x;
    const int tr = t >> 6, tc = t & 63;
    #pragma unroll
    for (int p = 0; p < 16; ++p) {
        int k = p * 4 + tr;
        Ts[k][tc] = W[(size_t)(kb + k) * N + nb + tc];
    }
    __syncthreads();
    const int nr = t >> 3, kc = t & 7;
    #pragma unroll
    for (int p = 0; p < 2; ++p) {
        int n = p * 32 + nr;
        bf16x8 o;
        #pragma unroll
        for (int x = 0; x < 8; ++x) o[x] = (bf16)Ts[kc * 8 + x][n];
        *(bf16x8*)&Wt[(size_t)(nb + n) * K + kb + kc * 8] = o;
    }
}

// ---------------------------------------------------------------------------
// m97-style GEMM core loop (shared by qkv-fused and Wo kernels).
// 128x128 tile, BK=32, 4 waves, 4x4 16x16 MFMA grid per wave.
// ---------------------------------------------------------------------------
__device__ __forceinline__ void gemm128_core(const bf16* __restrict__ A,
                                             const bf16* __restrict__ Bt,
                                             int K, int mb, int nb,
                                             bf16 (*As)[32], bf16 (*Bs)[32],
                                             f32x4 (*acc)[4],
                                             int w, int l16, int quad, int lane)
{
    const int m0 = (w & 1) * 64, n0 = (w >> 1) * 64;
    const int srow = lane >> 2, scol = (lane & 3) * 8;

    for (int kt = 0; kt < K; kt += 32) {
        __syncthreads();
        gload_lds16(&A [(size_t)(mb + w * 32 +      srow) * K + kt + scol], &As[w * 32     ][0]);
        gload_lds16(&A [(size_t)(mb + w * 32 + 16 + srow) * K + kt + scol], &As[w * 32 + 16][0]);
        gload_lds16(&Bt[(size_t)(nb + w * 32 +      srow) * K + kt + scol], &Bs[w * 32     ][0]);
        gload_lds16(&Bt[(size_t)(nb + w * 32 + 16 + srow) * K + kt + scol], &Bs[w * 32 + 16][0]);
        __syncthreads();

        bf16x8 af[4], bfr[4];
        #pragma unroll
        for (int t = 0; t < 4; ++t) af[t]  = *(const bf16x8*)&As[m0 + t * 16 + l16][quad * 8];
        #pragma unroll
        for (int u = 0; u < 4; ++u) bfr[u] = *(const bf16x8*)&Bs[n0 + u * 16 + l16][quad * 8];
        #pragma unroll
        for (int t = 0; t < 4; ++t)
            #pragma unroll
            for (int u = 0; u < 4; ++u)
                acc[t][u] = __builtin_amdgcn_mfma_f32_16x16x32_bf16(af[t], bfr[u], acc[t][u], 0, 0, 0);
    }
}

// Fused QKV projection: A[M,K] @ WqkvT[N=3072,K]^T with region routing:
// cols [0,2048) -> qOut row-major; [2048,2560) -> kOut row-major;
// [2560,3072) -> vT transposed. Region bounds are 128-multiples (block-uniform).
__global__ __launch_bounds__(256) void gemm_qkv_kernel(const bf16* __restrict__ A,
                                                       const bf16* __restrict__ Wt,
                                                       bf16* __restrict__ qOut,
                                                       bf16* __restrict__ kOut,
                                                       bf16* __restrict__ vOut,
                                                       int M, int K)
{
    __shared__ __attribute__((aligned(16))) bf16 As[128][32];
    __shared__ __attribute__((aligned(16))) bf16 Bs[128][32];
    const int tid = threadIdx.x, w = tid >> 6, lane = tid & 63;
    const int l16 = lane & 15, quad = lane >> 4;
    const int mb = blockIdx.x * 128, nb = blockIdx.y * 128;
    const int m0 = (w & 1) * 64, n0 = (w >> 1) * 64;

    f32x4 acc[4][4] = {};
    gemm128_core(A, Wt, K, mb, nb, As, Bs, acc, w, l16, quad, lane);

    #pragma unroll
    for (int t = 0; t < 4; ++t)
        #pragma unroll
        for (int u = 0; u < 4; ++u)
            #pragma unroll
            for (int r = 0; r < 4; ++r) {
                int row = mb + m0 + t * 16 + quad * 4 + r;
                int col = nb + n0 + u * 16 + l16;
                bf16 val = (bf16)acc[t][u][r];
                if (nb < 2048)       qOut[(size_t)row * HID + col] = val;
                else if (nb < 2560)  kOut[(size_t)row * KVD + (col - 2048)] = val;
                else                 vOut[(size_t)(col - 2560) * S_LEN + row] = val;
            }
}

// Plain GEMM (for Wo): C[M,N] = A @ Bt^T, f32 out.
__global__ __launch_bounds__(256) void gemm128_kernel(const bf16* __restrict__ A,
                                                      const bf16* __restrict__ Bt,
                                                      float* __restrict__ C,
                                                      int M, int N, int K)
{
    __shared__ __attribute__((aligned(16))) bf16 As[128][32];
    __shared__ __attribute__((aligned(16))) bf16 Bs[128][32];
    const int tid = threadIdx.x, w = tid >> 6, lane = tid & 63;
    const int l16 = lane & 15, quad = lane >> 4;
    const int mb = blockIdx.x * 128, nb = blockIdx.y * 128;
    const int m0 = (w & 1) * 64, n0 = (w >> 1) * 64;

    f32x4 acc[4][4] = {};
    gemm128_core(A, Bt, K, mb, nb, As, Bs, acc, w, l16, quad, lane);

    #pragma unroll
    for (int t = 0; t < 4; ++t)
        #pragma unroll
        for (int u = 0; u < 4; ++u)
            #pragma unroll
            for (int r = 0; r < 4; ++r) {
                int row = mb + m0 + t * 16 + quad * 4 + r;
                int col = nb + n0 + u * 16 + l16;
                C[(size_t)row * N + col] = acc[t][u][r];
            }
}

// ---------------------------------------------------------------------------
// In-place RoPE on bf16 buffer; cos/sin f32. Thread owns pair (d, d+64).
// ---------------------------------------------------------------------------
template<int HEADS>
__global__ __launch_bounds__(256) void rope_kernel(bf16* __restrict__ x,
                                                   const float* __restrict__ cosb,
                                                   const float* __restrict__ sinb)
{
    int idx = blockIdx.x * 256 + threadIdx.x;
    int s   = idx / (HEADS * 64);
    int rem = idx % (HEADS * 64);
    int h   = rem >> 6, d = rem & 63;
    size_t base = (size_t)s * (HEADS * 128) + h * 128 + d;
    float x0 = (float)x[base], x1 = (float)x[base + 64];
    float c0 = cosb[s * 128 + d], c1 = cosb[s * 128 + d + 64];
    float n0 = sinb[s * 128 + d], n1 = sinb[s * 128 + d + 64];
    x[base]      = (bf16)(x0 * c0 - x1 * n0);
    x[base + 64] = (bf16)(x1 * c1 + x0 * n1);
}

// ---------------------------------------------------------------------------
// Gate projection (full f32): graw[c][s] = log_sigmoid(hs[s,:] . Wg[:,c]).
// ---------------------------------------------------------------------------
__global__ __launch_bounds__(64) void gproj_kernel(const float* __restrict__ hs,
                                                   const float* __restrict__ Wg,
                                                   float* __restrict__ graw)
{
    int s = blockIdx.x, lane = threadIdx.x;
    float a0 = 0.f, a1 = 0.f, a2 = 0.f, a3 = 0.f;
    for (int kk = lane; kk < HID; kk += 64) {
        float h = hs[(size_t)s * HID + kk];
        const float* wr = &Wg[kk * 4];
        a0 += h * wr[0]; a1 += h * wr[1];
        a2 += h * wr[2]; a3 += h * wr[3];
    }
    #pragma unroll
    for (int off = 32; off >= 1; off >>= 1) {
        a0 += __shfl_xor(a0, off); a1 += __shfl_xor(a1, off);
        a2 += __shfl_xor(a2, off); a3 += __shfl_xor(a3, off);
    }
    if (lane == 0) {
        float vv[4] = {a0, a1, a2, a3};
        #pragma unroll
        for (int c = 0; c < 4; ++c) {
            float x = vv[c];
            graw[c * S_LEN + s] = fminf(x, 0.f) - log1pf(expf(-fabsf(x)));
        }
    }
}

// ---------------------------------------------------------------------------
// Inclusive cumsum over s per kv head.
// ---------------------------------------------------------------------------
__global__ __launch_bounds__(256) void cumsum_kernel(const float* __restrict__ graw,
                                                     float* __restrict__ G)
{
    int c = blockIdx.x, t = threadIdx.x;
    __shared__ float sums[256];
    float loc[8];
    float run = 0.f;
    #pragma unroll
    for (int i = 0; i < 8; ++i) { run += graw[c * S_LEN + t * 8 + i]; loc[i] = run; }
    sums[t] = run;
    __syncthreads();
    for (int off = 1; off < 256; off <<= 1) {
        float add = (t >= off) ? sums[t - off] : 0.f;
        __syncthreads();
        sums[t] += add;
        __syncthreads();
    }
    float offset = sums[t] - run;
    #pragma unroll
    for (int i = 0; i < 8; ++i) G[c * S_LEN + t * 8 + i] = offset + loc[i];
}

// ---------------------------------------------------------------------------
// Causal decay attention. Block = (64-query tile, head), qt reversed.
// K/V staged via global_load_lds into k-chunked layouts (64B row stride:
// conflict-free b128 frag reads). Decay factored: exp(Gi-Gj) =
// exp(Gi-Gt)*exp(Gt-Gj), Gt = G[jb] -> 8 exps/thread/iter.
// ---------------------------------------------------------------------------
__global__ __launch_bounds__(256) void attn_kernel(const bf16* __restrict__ q,
                                                   const bf16* __restrict__ k,
                                                   const bf16* __restrict__ vT,
                                                   const float* __restrict__ G,
                                                   bf16* __restrict__ out)
{
    const int qt = gridDim.x - 1 - blockIdx.x;       // long blocks first
    const int h = blockIdx.y, kvh = h >> 2;
    const int qb = qt * 64;
    const int tid = threadIdx.x, w = tid >> 6, lane = tid & 63;
    const int l16 = lane & 15, quad = lane >> 4;

    __shared__ __attribute__((aligned(16))) bf16 Ks4[4][64][32];   // [kc][j][d32]
    __shared__ __attribute__((aligned(16))) bf16 Vt4[2][128][32];  // [kk][d][j32]
    __shared__ __attribute__((aligned(16))) bf16 Sb[4][16][72];    // per-wave S [i][j]

    bf16x8 qf[4];
    const int qrow = qb + w * 16 + l16;
    #pragma unroll
    for (int kc = 0; kc < 4; ++kc)
        qf[kc] = *(const bf16x8*)&q[(size_t)qrow * HID + h * HD + kc * 32 + quad * 8];

    const int irow = qb + w * 16 + quad * 4;
    float Gq[4];
    #pragma unroll
    for (int r = 0; r < 4; ++r) Gq[r] = G[kvh * S_LEN + irow + r];

    // staging lane decomposition (16 rows x 32 cols per 1KB chunk)
    const int sr4 = lane >> 2, sc4 = (lane & 3) * 8;
    const int vkk = w >> 1, vdg = (w & 1) * 4;   // V: wave w -> j-chunk, d-group base

    f32x4 acco[8] = {};
    float den[4] = {0.f, 0.f, 0.f, 0.f};

    for (int kt = 0; kt <= qt; ++kt) {
        const int jb = kt * 64;
        __syncthreads();
        // K tile: wave w stages column-chunk kc=w, 4 row-groups of 16
        #pragma unroll
        for (int rg = 0; rg < 4; ++rg)
            gload_lds16(&k[(size_t)(jb + rg * 16 + sr4) * KVD + kvh * HD + w * 32 + sc4],
                        &Ks4[w][rg * 16][0]);
        // V tile: wave w stages j-chunk vkk, d-groups vdg..vdg+3
        #pragma unroll
        for (int it = 0; it < 4; ++it)
            gload_lds16(&vT[(size_t)(kvh * HD + (vdg + it) * 16 + sr4) * S_LEN + jb + vkk * 32 + sc4],
                        &Vt4[vkk][(vdg + it) * 16][0]);
        __syncthreads();

        // S = q @ K^T
        f32x4 accs[4] = {};
        #pragma unroll
        for (int t = 0; t < 4; ++t)
            #pragma unroll
            for (int kc = 0; kc < 4; ++kc) {
                bf16x8 bfr = *(const bf16x8*)&Ks4[kc][t * 16 + l16][quad * 8];
                accs[t] = __builtin_amdgcn_mfma_f32_16x16x32_bf16(qf[kc], bfr, accs[t], 0, 0, 0);
            }

        // factored decay + mask; accumulate den; stage S into A-layout
        const float Gt = G[kvh * S_LEN + jb];
        float sr[4];
        #pragma unroll
        for (int r = 0; r < 4; ++r) sr[r] = SCALE2 * __expf(Gq[r] - Gt);  // <=SCALE2
        #pragma unroll
        for (int t = 0; t < 4; ++t) {
            int j = jb + t * 16 + l16;
            float colF = __expf(fminf(Gt - G[kvh * S_LEN + j], 85.f));    // >=1, finite
            #pragma unroll
            for (int r = 0; r < 4; ++r) {
                float d0 = accs[t][r];
                float sc = (j <= irow + r) ? d0 * d0 * sr[r] * colF : 0.f;
                den[r] += sc;
                Sb[w][quad * 4 + r][t * 16 + l16] = (bf16)sc;
            }
        }
        // no barrier: Sb[w] written & read by the same wave

        // O += S @ V
        #pragma unroll
        for (int kk = 0; kk < 2; ++kk) {
            bf16x8 af = *(const bf16x8*)&Sb[w][l16][kk * 32 + quad * 8];
            #pragma unroll
            for (int dt = 0; dt < 8; ++dt) {
                bf16x8 bfr = *(const bf16x8*)&Vt4[kk][dt * 16 + l16][quad * 8];
                acco[dt] = __builtin_amdgcn_mfma_f32_16x16x32_bf16(af, bfr, acco[dt], 0, 0, 0);
            }
        }
    }

    #pragma unroll
    for (int r = 0; r < 4; ++r) {
        #pragma unroll
        for (int off = 1; off < 16; off <<= 1) den[r] += __shfl_xor(den[r], off);
        den[r] = 1.f / fmaxf(den[r], 1.f);
    }
    #pragma unroll
    for (int dt = 0; dt < 8; ++dt)
        #pragma unroll
        for (int r = 0; r < 4; ++r)
            out[(size_t)(irow + r) * HID + h * HD + dt * 16 + l16] = (bf16)(acco[dt][r] * den[r]);
}

// ---------------------------------------------------------------------------
extern "C" void kernel_launch(void* const* d_in, const int* in_sizes, int n_in,
                              void* d_out, int out_size, void* d_ws, size_t ws_size,
                              hipStream_t stream)
{
    const float* hs   = (const float*)d_in[0];
    const float* cosb = (const float*)d_in[1];
    const float* sinb = (const float*)d_in[2];
    const float* Wq   = (const float*)d_in[3];
    const float* Wk   = (const float*)d_in[4];
    const float* Wv   = (const float*)d_in[5];
    const float* Wg   = (const float*)d_in[6];
    const float* Wo   = (const float*)d_in[7];
    float* out = (float*)d_out;

    char* p = (char*)d_ws;
    bf16*  qbuf  = (bf16*)p;  p += (size_t)S_LEN * HID * 2;    // 8 MB
    bf16*  kbuf  = (bf16*)p;  p += (size_t)S_LEN * KVD * 2;    // 2 MB
    bf16*  vT    = (bf16*)p;  p += (size_t)S_LEN * KVD * 2;    // 2 MB ([KVD][S])
    bf16*  abuf  = (bf16*)p;  p += (size_t)S_LEN * HID * 2;    // 8 MB
    bf16*  hsb   = (bf16*)p;  p += (size_t)S_LEN * HID * 2;    // 8 MB
    bf16*  WcatT = (bf16*)p;  p += (size_t)NQKV * HID * 2;     // 12 MB ([3072][2048])
    bf16*  WoT   = (bf16*)p;  p += (size_t)HID * HID * 2;      // 8 MB
    float* graw  = (float*)p; p += (size_t)NKV * S_LEN * 4;
    float* G     = (float*)p; p += (size_t)NKV * S_LEN * 4;

    // pre-pass: bf16 convert + weight transposes into concat buffer
    cvt_kernel<<<(S_LEN * HID) / (256 * 8), 256, 0, stream>>>(hs, hsb, S_LEN * HID);
    transpose_cvt_kernel<<<dim3(32, 32), 256, 0, stream>>>(Wq, WcatT,                          HID, HID);
    transpose_cvt_kernel<<<dim3(32,  8), 256, 0, stream>>>(Wk, WcatT + (size_t)2048 * HID,     HID, KVD);
    transpose_cvt_kernel<<<dim3(32,  8), 256, 0, stream>>>(Wv, WcatT + (size_t)2560 * HID,     HID, KVD);
    transpose_cvt_kernel<<<dim3(32, 32), 256, 0, stream>>>(Wo, WoT, HID, HID);

    // fused QKV projection (384 blocks)
    gemm_qkv_kernel<<<dim3(16, 24), 256, 0, stream>>>(hsb, WcatT, qbuf, kbuf, vT, S_LEN, HID);

    gproj_kernel<<<S_LEN, 64, 0, stream>>>(hs, Wg, graw);
    cumsum_kernel<<<NKV, 256, 0, stream>>>(graw, G);
    rope_kernel<NH ><<<(S_LEN * NH  * 64) / 256, 256, 0, stream>>>(qbuf, cosb, sinb);
    rope_kernel<NKV><<<(S_LEN * NKV * 64) / 256, 256, 0, stream>>>(kbuf, cosb, sinb);

    attn_kernel<<<dim3(32, NH), 256, 0, stream>>>(qbuf, kbuf, vT, G, abuf);

    gemm128_kernel<<<dim3(16, 16), 256, 0, stream>>>(abuf, WoT, out, S_LEN, HID, HID);
}

// Round 6
// 310.154 us; speedup vs baseline: 1.9533x; 1.0071x over previous
//
#include <hip/hip_runtime.h>
#include <hip/hip_bf16.h>

#define S_LEN 2048
#define HID   2048
#define NH    16
#define NKV   4
#define HD    128
#define KVD   512            // NKV*HD
#define NQKV  3072           // HID + KVD + KVD
#define SCALE2 0.0078125f    // (D^-0.5)^2 = 1/128
#define NCH   80             // j-chunk slots per head: sum_{qt} ceil((qt+1)/8)

typedef __bf16 bf16;
typedef __attribute__((ext_vector_type(8))) __bf16 bf16x8;
typedef __attribute__((ext_vector_type(4))) float f32x4;

// async global->LDS, 16B per lane; LDS dest is wave-uniform base + lane*16
__device__ __forceinline__ void gload_lds16(const bf16* g, bf16* l) {
    __builtin_amdgcn_global_load_lds((const __attribute__((address_space(1))) void*)g,
                                     (__attribute__((address_space(3))) void*)l, 16, 0, 0);
}

// ---------------------------------------------------------------------------
__global__ __launch_bounds__(256) void cvt_kernel(const float* __restrict__ in,
                                                  bf16* __restrict__ out, int n)
{
    int i = (blockIdx.x * 256 + threadIdx.x) * 8;
    if (i >= n) return;
    const float4* q = (const float4*)&in[i];
    float4 a = q[0], b = q[1];
    bf16x8 r;
    r[0]=(bf16)a.x; r[1]=(bf16)a.y; r[2]=(bf16)a.z; r[3]=(bf16)a.w;
    r[4]=(bf16)b.x; r[5]=(bf16)b.y; r[6]=(bf16)b.z; r[7]=(bf16)b.w;
    *(bf16x8*)&out[i] = r;
}

__global__ __launch_bounds__(256) void zero_kernel(float* __restrict__ p, int n)
{
    int i = (blockIdx.x * 256 + threadIdx.x) * 4;
    if (i < n) *(float4*)&p[i] = make_float4(0.f, 0.f, 0.f, 0.f);
}

// ---------------------------------------------------------------------------
// W[K][N] f32 -> Wt[N][K] bf16, 64x64 LDS tile (pad 65).
// ---------------------------------------------------------------------------
__global__ __launch_bounds__(256) void transpose_cvt_kernel(const float* __restrict__ W,
                                                            bf16* __restrict__ Wt,
                                                            int K, int N)
{
    __shared__ float Ts[64][65];
    const int kb = blockIdx.x * 64, nb = blockIdx.y * 64;
    const int t = threadIdx.x;
    const int tr = t >> 6, tc = t & 63;
    #pragma unroll
    for (int p = 0; p < 16; ++p) {
        int k = p * 4 + tr;
        Ts[k][tc] = W[(size_t)(kb + k) * N + nb + tc];
    }
    __syncthreads();
    const int nr = t >> 3, kc = t & 7;
    #pragma unroll
    for (int p = 0; p < 2; ++p) {
        int n = p * 32 + nr;
        bf16x8 o;
        #pragma unroll
        for (int x = 0; x < 8; ++x) o[x] = (bf16)Ts[kc * 8 + x][n];
        *(bf16x8*)&Wt[(size_t)(nb + n) * K + kb + kc * 8] = o;
    }
}

// ---------------------------------------------------------------------------
// m97-style GEMM core loop: 128x128 tile, BK=32, 4 waves, 4x4 MFMA grid.
// ---------------------------------------------------------------------------
__device__ __forceinline__ void gemm128_core(const bf16* __restrict__ A,
                                             const bf16* __restrict__ Bt,
                                             int K, int k0, int k1, int mb, int nb,
                                             bf16 (*As)[32], bf16 (*Bs)[32],
                                             f32x4 (*acc)[4],
                                             int w, int l16, int quad, int lane)
{
    const int m0 = (w & 1) * 64, n0 = (w >> 1) * 64;
    const int srow = lane >> 2, scol = (lane & 3) * 8;

    for (int kt = k0; kt < k1; kt += 32) {
        __syncthreads();
        gload_lds16(&A [(size_t)(mb + w * 32 +      srow) * K + kt + scol], &As[w * 32     ][0]);
        gload_lds16(&A [(size_t)(mb + w * 32 + 16 + srow) * K + kt + scol], &As[w * 32 + 16][0]);
        gload_lds16(&Bt[(size_t)(nb + w * 32 +      srow) * K + kt + scol], &Bs[w * 32     ][0]);
        gload_lds16(&Bt[(size_t)(nb + w * 32 + 16 + srow) * K + kt + scol], &Bs[w * 32 + 16][0]);
        __syncthreads();

        bf16x8 af[4], bfr[4];
        #pragma unroll
        for (int t = 0; t < 4; ++t) af[t]  = *(const bf16x8*)&As[m0 + t * 16 + l16][quad * 8];
        #pragma unroll
        for (int u = 0; u < 4; ++u) bfr[u] = *(const bf16x8*)&Bs[n0 + u * 16 + l16][quad * 8];
        #pragma unroll
        for (int t = 0; t < 4; ++t)
            #pragma unroll
            for (int u = 0; u < 4; ++u)
                acc[t][u] = __builtin_amdgcn_mfma_f32_16x16x32_bf16(af[t], bfr[u], acc[t][u], 0, 0, 0);
    }
}

// Fused QKV projection with region routing (bounds are 128-multiples).
__global__ __launch_bounds__(256) void gemm_qkv_kernel(const bf16* __restrict__ A,
                                                       const bf16* __restrict__ Wt,
                                                       bf16* __restrict__ qOut,
                                                       bf16* __restrict__ kOut,
                                                       bf16* __restrict__ vOut,
                                                       int M, int K)
{
    __shared__ __attribute__((aligned(16))) bf16 As[128][32];
    __shared__ __attribute__((aligned(16))) bf16 Bs[128][32];
    const int tid = threadIdx.x, w = tid >> 6, lane = tid & 63;
    const int l16 = lane & 15, quad = lane >> 4;
    const int mb = blockIdx.x * 128, nb = blockIdx.y * 128;
    const int m0 = (w & 1) * 64, n0 = (w >> 1) * 64;

    f32x4 acc[4][4] = {};
    gemm128_core(A, Wt, K, 0, K, mb, nb, As, Bs, acc, w, l16, quad, lane);

    #pragma unroll
    for (int t = 0; t < 4; ++t)
        #pragma unroll
        for (int u = 0; u < 4; ++u)
            #pragma unroll
            for (int r = 0; r < 4; ++r) {
                int row = mb + m0 + t * 16 + quad * 4 + r;
                int col = nb + n0 + u * 16 + l16;
                bf16 val = (bf16)acc[t][u][r];
                if (nb < 2048)       qOut[(size_t)row * HID + col] = val;
                else if (nb < 2560)  kOut[(size_t)row * KVD + (col - 2048)] = val;
                else                 vOut[(size_t)(col - 2560) * S_LEN + row] = val;
            }
}

// Wo GEMM, split-K=2 over gridDim.z, accumulating into pre-zeroed f32 C
// via native f32 atomics (disjoint addresses across z -> ~store rate).
__global__ __launch_bounds__(256) void gemm_wo_kernel(const bf16* __restrict__ A,
                                                      const bf16* __restrict__ Bt,
                                                      float* __restrict__ C,
                                                      int M, int N, int K)
{
    __shared__ __attribute__((aligned(16))) bf16 As[128][32];
    __shared__ __attribute__((aligned(16))) bf16 Bs[128][32];
    const int tid = threadIdx.x, w = tid >> 6, lane = tid & 63;
    const int l16 = lane & 15, quad = lane >> 4;
    const int mb = blockIdx.x * 128, nb = blockIdx.y * 128;
    const int m0 = (w & 1) * 64, n0 = (w >> 1) * 64;
    const int kh = K >> 1, k0 = blockIdx.z * kh;

    f32x4 acc[4][4] = {};
    gemm128_core(A, Bt, K, k0, k0 + kh, mb, nb, As, Bs, acc, w, l16, quad, lane);

    #pragma unroll
    for (int t = 0; t < 4; ++t)
        #pragma unroll
        for (int u = 0; u < 4; ++u)
            #pragma unroll
            for (int r = 0; r < 4; ++r) {
                int row = mb + m0 + t * 16 + quad * 4 + r;
                int col = nb + n0 + u * 16 + l16;
                unsafeAtomicAdd(&C[(size_t)row * N + col], acc[t][u][r]);
            }
}

// ---------------------------------------------------------------------------
template<int HEADS>
__global__ __launch_bounds__(256) void rope_kernel(bf16* __restrict__ x,
                                                   const float* __restrict__ cosb,
                                                   const float* __restrict__ sinb)
{
    int idx = blockIdx.x * 256 + threadIdx.x;
    int s   = idx / (HEADS * 64);
    int rem = idx % (HEADS * 64);
    int h   = rem >> 6, d = rem & 63;
    size_t base = (size_t)s * (HEADS * 128) + h * 128 + d;
    float x0 = (float)x[base], x1 = (float)x[base + 64];
    float c0 = cosb[s * 128 + d], c1 = cosb[s * 128 + d + 64];
    float n0 = sinb[s * 128 + d], n1 = sinb[s * 128 + d + 64];
    x[base]      = (bf16)(x0 * c0 - x1 * n0);
    x[base + 64] = (bf16)(x1 * c1 + x0 * n1);
}

// ---------------------------------------------------------------------------
__global__ __launch_bounds__(64) void gproj_kernel(const float* __restrict__ hs,
                                                   const float* __restrict__ Wg,
                                                   float* __restrict__ graw)
{
    int s = blockIdx.x, lane = threadIdx.x;
    float a0 = 0.f, a1 = 0.f, a2 = 0.f, a3 = 0.f;
    for (int kk = lane; kk < HID; kk += 64) {
        float h = hs[(size_t)s * HID + kk];
        const float* wr = &Wg[kk * 4];
        a0 += h * wr[0]; a1 += h * wr[1];
        a2 += h * wr[2]; a3 += h * wr[3];
    }
    #pragma unroll
    for (int off = 32; off >= 1; off >>= 1) {
        a0 += __shfl_xor(a0, off); a1 += __shfl_xor(a1, off);
        a2 += __shfl_xor(a2, off); a3 += __shfl_xor(a3, off);
    }
    if (lane == 0) {
        float vv[4] = {a0, a1, a2, a3};
        #pragma unroll
        for (int c = 0; c < 4; ++c) {
            float x = vv[c];
            graw[c * S_LEN + s] = fminf(x, 0.f) - log1pf(expf(-fabsf(x)));
        }
    }
}

__global__ __launch_bounds__(256) void cumsum_kernel(const float* __restrict__ graw,
                                                     float* __restrict__ G)
{
    int c = blockIdx.x, t = threadIdx.x;
    __shared__ float sums[256];
    float loc[8];
    float run = 0.f;
    #pragma unroll
    for (int i = 0; i < 8; ++i) { run += graw[c * S_LEN + t * 8 + i]; loc[i] = run; }
    sums[t] = run;
    __syncthreads();
    for (int off = 1; off < 256; off <<= 1) {
        float add = (t >= off) ? sums[t - off] : 0.f;
        __syncthreads();
        sums[t] += add;
        __syncthreads();
    }
    float offset = sums[t] - run;
    #pragma unroll
    for (int i = 0; i < 8; ++i) G[c * S_LEN + t * 8 + i] = offset + loc[i];
}

// ---------------------------------------------------------------------------
// Causal decay attention, j-split. Block = (qt, j-chunk of <=8 tiles, head).
// Per head: qt in group g=qt/8 has g+1 chunks; 80 blocks/head.
// qt<8 (single chunk): final bf16 out. Else: f32 partial O + partial den.
// ---------------------------------------------------------------------------
__global__ __launch_bounds__(256) void attn_kernel(const bf16* __restrict__ q,
                                                   const bf16* __restrict__ k,
                                                   const bf16* __restrict__ vT,
                                                   const float* __restrict__ G,
                                                   bf16* __restrict__ out,
                                                   float* __restrict__ pO,
                                                   float* __restrict__ pden)
{
    // decode (qt, chunk) from blockIdx.x
    int rem = blockIdx.x, qt = 0, cch = 0;
    #pragma unroll
    for (int g = 0; g < 4; ++g) {
        int sz = 8 * (g + 1);
        if (rem < sz) { qt = g * 8 + rem / (g + 1); cch = rem % (g + 1); break; }
        rem -= sz;
    }
    const int gg = qt >> 3, nc = gg + 1;
    const int jt0 = cch * 8, jt1 = min(qt + 1, jt0 + 8);

    const int h = blockIdx.y, kvh = h >> 2;
    const int qb = qt * 64;
    const int tid = threadIdx.x, w = tid >> 6, lane = tid & 63;
    const int l16 = lane & 15, quad = lane >> 4;

    __shared__ __attribute__((aligned(16))) bf16 Ks4[4][64][32];   // [kc][j][d32]
    __shared__ __attribute__((aligned(16))) bf16 Vt4[2][128][32];  // [kk][d][j32]
    __shared__ __attribute__((aligned(16))) bf16 Sb[4][16][68];    // pad 68: quad stride 8 mod 32

    bf16x8 qf[4];
    const int qrow = qb + w * 16 + l16;
    #pragma unroll
    for (int kc = 0; kc < 4; ++kc)
        qf[kc] = *(const bf16x8*)&q[(size_t)qrow * HID + h * HD + kc * 32 + quad * 8];

    const int irow = qb + w * 16 + quad * 4;
    float Gq[4];
    #pragma unroll
    for (int r = 0; r < 4; ++r) Gq[r] = G[kvh * S_LEN + irow + r];

    const int sr4 = lane >> 2, sc4 = (lane & 3) * 8;
    const int vkk = w >> 1, vdg = (w & 1) * 4;

    f32x4 acco[8] = {};
    float den[4] = {0.f, 0.f, 0.f, 0.f};

    for (int kt = jt0; kt < jt1; ++kt) {
        const int jb = kt * 64;
        __syncthreads();
        #pragma unroll
        for (int rg = 0; rg < 4; ++rg)
            gload_lds16(&k[(size_t)(jb + rg * 16 + sr4) * KVD + kvh * HD + w * 32 + sc4],
                        &Ks4[w][rg * 16][0]);
        #pragma unroll
        for (int it = 0; it < 4; ++it)
            gload_lds16(&vT[(size_t)(kvh * HD + (vdg + it) * 16 + sr4) * S_LEN + jb + vkk * 32 + sc4],
                        &Vt4[vkk][(vdg + it) * 16][0]);
        __syncthreads();

        // S = q @ K^T
        f32x4 accs[4] = {};
        #pragma unroll
        for (int t = 0; t < 4; ++t)
            #pragma unroll
            for (int kc = 0; kc < 4; ++kc) {
                bf16x8 bfr = *(const bf16x8*)&Ks4[kc][t * 16 + l16][quad * 8];
                accs[t] = __builtin_amdgcn_mfma_f32_16x16x32_bf16(qf[kc], bfr, accs[t], 0, 0, 0);
            }

        // factored decay + mask; den; stage S into A-layout
        const float Gt = G[kvh * S_LEN + jb];
        float sr[4];
        #pragma unroll
        for (int r = 0; r < 4; ++r) sr[r] = SCALE2 * __expf(Gq[r] - Gt);
        #pragma unroll
        for (int t = 0; t < 4; ++t) {
            int j = jb + t * 16 + l16;
            float colF = __expf(fminf(Gt - G[kvh * S_LEN + j], 85.f));
            #pragma unroll
            for (int r = 0; r < 4; ++r) {
                float d0 = accs[t][r];
                float sc = (j <= irow + r) ? d0 * d0 * sr[r] * colF : 0.f;
                den[r] += sc;
                Sb[w][quad * 4 + r][t * 16 + l16] = (bf16)sc;
            }
        }
        // no barrier: Sb[w] is wave-private

        // O += S @ V
        #pragma unroll
        for (int kk = 0; kk < 2; ++kk) {
            bf16x8 af = *(const bf16x8*)&Sb[w][l16][kk * 32 + quad * 8];
            #pragma unroll
            for (int dt = 0; dt < 8; ++dt) {
                bf16x8 bfr = *(const bf16x8*)&Vt4[kk][dt * 16 + l16][quad * 8];
                acco[dt] = __builtin_amdgcn_mfma_f32_16x16x32_bf16(af, bfr, acco[dt], 0, 0, 0);
            }
        }
    }

    // reduce den across the 16 j-lanes
    #pragma unroll
    for (int r = 0; r < 4; ++r) {
        #pragma unroll
        for (int off = 1; off < 16; off <<= 1) den[r] += __shfl_xor(den[r], off);
    }

    if (nc == 1) {
        float dinv[4];
        #pragma unroll
        for (int r = 0; r < 4; ++r) dinv[r] = 1.f / fmaxf(den[r], 1.f);
        #pragma unroll
        for (int dt = 0; dt < 8; ++dt)
            #pragma unroll
            for (int r = 0; r < 4; ++r)
                out[(size_t)(irow + r) * HID + h * HD + dt * 16 + l16] =
                    (bf16)(acco[dt][r] * dinv[r]);
    } else {
        const int slot = h * NCH + 4 * gg * (gg + 1) + (qt & 7) * (gg + 1) + cch;
        float* po = &pO[(size_t)slot * 8192];
        const int lr = w * 16 + quad * 4;   // local row base
        #pragma unroll
        for (int dt = 0; dt < 8; ++dt)
            #pragma unroll
            for (int r = 0; r < 4; ++r)
                po[(lr + r) * 128 + dt * 16 + l16] = acco[dt][r];
        if (l16 == 0) {
            #pragma unroll
            for (int r = 0; r < 4; ++r) pden[slot * 64 + lr + r] = den[r];
        }
    }
}

// Combine partial chunks for qt >= 8. Grid: 16 heads x 24 qts.
__global__ __launch_bounds__(256) void attn_reduce_kernel(const float* __restrict__ pO,
                                                          const float* __restrict__ pden,
                                                          bf16* __restrict__ out)
{
    const int p = blockIdx.x;
    const int h = p / 24, qt = 8 + p % 24;
    const int gg = qt >> 3, nc = gg + 1;
    const int base = h * NCH + 4 * gg * (gg + 1) + (qt & 7) * (gg + 1);
    const int qb = qt * 64;
    const int tid = threadIdx.x;

    __shared__ float sden[64];
    if (tid < 64) {
        float s = 0.f;
        for (int c = 0; c < nc; ++c) s += pden[(base + c) * 64 + tid];
        sden[tid] = 1.f / fmaxf(s, 1.f);
    }
    __syncthreads();

    #pragma unroll
    for (int i = 0; i < 8; ++i) {
        int e = i * 1024 + tid * 4;          // 4 contiguous f32
        float4 s = make_float4(0.f, 0.f, 0.f, 0.f);
        for (int c = 0; c < nc; ++c) {
            float4 v = *(const float4*)&pO[(size_t)(base + c) * 8192 + e];
            s.x += v.x; s.y += v.y; s.z += v.z; s.w += v.w;
        }
        int lr = e >> 7, col = e & 127;
        float di = sden[lr];
        bf16* o = &out[(size_t)(qb + lr) * HID + h * HD + col];
        o[0] = (bf16)(s.x * di); o[1] = (bf16)(s.y * di);
        o[2] = (bf16)(s.z * di); o[3] = (bf16)(s.w * di);
    }
}

// ---------------------------------------------------------------------------
extern "C" void kernel_launch(void* const* d_in, const int* in_sizes, int n_in,
                              void* d_out, int out_size, void* d_ws, size_t ws_size,
                              hipStream_t stream)
{
    const float* hs   = (const float*)d_in[0];
    const float* cosb = (const float*)d_in[1];
    const float* sinb = (const float*)d_in[2];
    const float* Wq   = (const float*)d_in[3];
    const float* Wk   = (const float*)d_in[4];
    const float* Wv   = (const float*)d_in[5];
    const float* Wg   = (const float*)d_in[6];
    const float* Wo   = (const float*)d_in[7];
    float* out = (float*)d_out;

    char* p = (char*)d_ws;
    bf16*  qbuf  = (bf16*)p;  p += (size_t)S_LEN * HID * 2;    // 8 MB
    bf16*  kbuf  = (bf16*)p;  p += (size_t)S_LEN * KVD * 2;    // 2 MB
    bf16*  vT    = (bf16*)p;  p += (size_t)S_LEN * KVD * 2;    // 2 MB ([KVD][S])
    bf16*  abuf  = (bf16*)p;  p += (size_t)S_LEN * HID * 2;    // 8 MB
    bf16*  hsb   = (bf16*)p;  p += (size_t)S_LEN * HID * 2;    // 8 MB
    bf16*  WcatT = (bf16*)p;  p += (size_t)NQKV * HID * 2;     // 12 MB
    bf16*  WoT   = (bf16*)p;  p += (size_t)HID * HID * 2;      // 8 MB
    float* graw  = (float*)p; p += (size_t)NKV * S_LEN * 4;
    float* G     = (float*)p; p += (size_t)NKV * S_LEN * 4;
    float* pO    = (float*)p; p += (size_t)NH * NCH * 8192 * 4; // 41.9 MB
    float* pden  = (float*)p; p += (size_t)NH * NCH * 64 * 4;   // 0.33 MB

    // pre-pass
    cvt_kernel<<<(S_LEN * HID) / (256 * 8), 256, 0, stream>>>(hs, hsb, S_LEN * HID);
    transpose_cvt_kernel<<<dim3(32, 32), 256, 0, stream>>>(Wq, WcatT,                      HID, HID);
    transpose_cvt_kernel<<<dim3(32,  8), 256, 0, stream>>>(Wk, WcatT + (size_t)2048 * HID, HID, KVD);
    transpose_cvt_kernel<<<dim3(32,  8), 256, 0, stream>>>(Wv, WcatT + (size_t)2560 * HID, HID, KVD);
    transpose_cvt_kernel<<<dim3(32, 32), 256, 0, stream>>>(Wo, WoT, HID, HID);
    zero_kernel<<<(S_LEN * HID) / (256 * 4), 256, 0, stream>>>(out, S_LEN * HID);

    // fused QKV projection
    gemm_qkv_kernel<<<dim3(16, 24), 256, 0, stream>>>(hsb, WcatT, qbuf, kbuf, vT, S_LEN, HID);

    gproj_kernel<<<S_LEN, 64, 0, stream>>>(hs, Wg, graw);
    cumsum_kernel<<<NKV, 256, 0, stream>>>(graw, G);
    rope_kernel<NH ><<<(S_LEN * NH  * 64) / 256, 256, 0, stream>>>(qbuf, cosb, sinb);
    rope_kernel<NKV><<<(S_LEN * NKV * 64) / 256, 256, 0, stream>>>(kbuf, cosb, sinb);

    // j-split attention + combine
    attn_kernel<<<dim3(NCH, NH), 256, 0, stream>>>(qbuf, kbuf, vT, G, abuf, pO, pden);
    attn_reduce_kernel<<<NH * 24, 256, 0, stream>>>(pO, pden, abuf);

    // output projection, split-K=2 atomic accumulate
    gemm_wo_kernel<<<dim3(16, 16, 2), 256, 0, stream>>>(abuf, WoT, out, S_LEN, HID, HID);
}

// Round 8
// 300.520 us; speedup vs baseline: 2.0160x; 1.0321x over previous
//
#include <hip/hip_runtime.h>
#include <hip/hip_bf16.h>

#define S_LEN 2048
#define HID   2048
#define NH    16
#define NKV   4
#define HD    128
#define KVD   512            // NKV*HD
#define NQKV  3072           // HID + KVD + KVD
#define SCALE2 0.0078125f    // (D^-0.5)^2 = 1/128
#define NCH   80             // j-chunk slots per head: sum_{qt} ceil((qt+1)/8)

typedef __bf16 bf16;
typedef __attribute__((ext_vector_type(8))) __bf16 bf16x8;
typedef __attribute__((ext_vector_type(4))) float f32x4;

// async global->LDS, 16B per lane; LDS dest is wave-uniform base + lane*16
__device__ __forceinline__ void gload_lds16(const bf16* g, bf16* l) {
    __builtin_amdgcn_global_load_lds((const __attribute__((address_space(1))) void*)g,
                                     (__attribute__((address_space(3))) void*)l, 16, 0, 0);
}

// ---------------------------------------------------------------------------
// Fused pre-pass. Region-decoded grid (all regions independent):
//   [0,2048)    : hs f32 -> hsb bf16
//   [2048,3072) : Wq transpose-cvt -> WcatT[0]
//   [3072,3328) : Wk -> WcatT[2048*HID]
//   [3328,3584) : Wv -> WcatT[2560*HID]
//   [3584,4608) : Wo -> WoT
//   [4608,6656) : zero d_out
//   [6656,7168) : gate projection, one wave per s
// ---------------------------------------------------------------------------
__device__ __forceinline__ void transpose_tile(const float* __restrict__ W,
                                               bf16* __restrict__ Wt,
                                               int K, int N, int bx, int by,
                                               int t, float (*Ts)[65])
{
    const int kb = bx * 64, nb = by * 64;
    const int tr = t >> 6, tc = t & 63;
    #pragma unroll
    for (int p = 0; p < 16; ++p) {
        int k = p * 4 + tr;
        Ts[k][tc] = W[(size_t)(kb + k) * N + nb + tc];
    }
    __syncthreads();
    const int nr = t >> 3, kc = t & 7;
    #pragma unroll
    for (int p = 0; p < 2; ++p) {
        int n = p * 32 + nr;
        bf16x8 o;
        #pragma unroll
        for (int x = 0; x < 8; ++x) o[x] = (bf16)Ts[kc * 8 + x][n];
        *(bf16x8*)&Wt[(size_t)(nb + n) * K + kb + kc * 8] = o;
    }
}

__global__ __launch_bounds__(256) void prep_kernel(const float* __restrict__ hs,
                                                   const float* __restrict__ Wq,
                                                   const float* __restrict__ Wk,
                                                   const float* __restrict__ Wv,
                                                   const float* __restrict__ Wo,
                                                   const float* __restrict__ Wg,
                                                   bf16* __restrict__ hsb,
                                                   bf16* __restrict__ WcatT,
                                                   bf16* __restrict__ WoT,
                                                   float* __restrict__ graw,
                                                   float* __restrict__ outz)
{
    __shared__ float Ts[64][65];
    const int b = blockIdx.x, tid = threadIdx.x;

    if (b < 2048) {                                   // cvt hs -> hsb
        int i = (b * 256 + tid) * 8;
        const float4* qp = (const float4*)&hs[i];
        float4 a = qp[0], c = qp[1];
        bf16x8 r;
        r[0]=(bf16)a.x; r[1]=(bf16)a.y; r[2]=(bf16)a.z; r[3]=(bf16)a.w;
        r[4]=(bf16)c.x; r[5]=(bf16)c.y; r[6]=(bf16)c.z; r[7]=(bf16)c.w;
        *(bf16x8*)&hsb[i] = r;
    } else if (b < 3072) {
        int lb = b - 2048;
        transpose_tile(Wq, WcatT, HID, HID, lb >> 5, lb & 31, tid, Ts);
    } else if (b < 3328) {
        int lb = b - 3072;
        transpose_tile(Wk, WcatT + (size_t)2048 * HID, HID, KVD, lb >> 3, lb & 7, tid, Ts);
    } else if (b < 3584) {
        int lb = b - 3328;
        transpose_tile(Wv, WcatT + (size_t)2560 * HID, HID, KVD, lb >> 3, lb & 7, tid, Ts);
    } else if (b < 4608) {
        int lb = b - 3584;
        transpose_tile(Wo, WoT, HID, HID, lb >> 5, lb & 31, tid, Ts);
    } else if (b < 6656) {                            // zero d_out
        int i = ((b - 4608) * 256 + tid) * 8;
        float4 z = make_float4(0.f, 0.f, 0.f, 0.f);
        *(float4*)&outz[i] = z;
        *(float4*)&outz[i + 4] = z;
    } else {                                          // gproj: wave per s
        const int w = tid >> 6, lane = tid & 63;
        const int s = (b - 6656) * 4 + w;
        float a0 = 0.f, a1 = 0.f, a2 = 0.f, a3 = 0.f;
        for (int kk = lane; kk < HID; kk += 64) {
            float h = hs[(size_t)s * HID + kk];
            const float* wr = &Wg[kk * 4];
            a0 += h * wr[0]; a1 += h * wr[1];
            a2 += h * wr[2]; a3 += h * wr[3];
        }
        #pragma unroll
        for (int off = 32; off >= 1; off >>= 1) {
            a0 += __shfl_xor(a0, off); a1 += __shfl_xor(a1, off);
            a2 += __shfl_xor(a2, off); a3 += __shfl_xor(a3, off);
        }
        if (lane == 0) {
            float vv[4] = {a0, a1, a2, a3};
            #pragma unroll
            for (int c = 0; c < 4; ++c) {
                float x = vv[c];
                graw[c * S_LEN + s] = fminf(x, 0.f) - log1pf(expf(-fabsf(x)));
            }
        }
    }
}

// ---------------------------------------------------------------------------
// Inclusive cumsum over s per kv head.
// ---------------------------------------------------------------------------
__global__ __launch_bounds__(256) void cumsum_kernel(const float* __restrict__ graw,
                                                     float* __restrict__ G)
{
    int c = blockIdx.x, t = threadIdx.x;
    __shared__ float sums[256];
    float loc[8];
    float run = 0.f;
    #pragma unroll
    for (int i = 0; i < 8; ++i) { run += graw[c * S_LEN + t * 8 + i]; loc[i] = run; }
    sums[t] = run;
    __syncthreads();
    for (int off = 1; off < 256; off <<= 1) {
        float add = (t >= off) ? sums[t - off] : 0.f;
        __syncthreads();
        sums[t] += add;
        __syncthreads();
    }
    float offset = sums[t] - run;
    #pragma unroll
    for (int i = 0; i < 8; ++i) G[c * S_LEN + t * 8 + i] = offset + loc[i];
}

// ---------------------------------------------------------------------------
// m97-style GEMM core loop: 128x128 tile, BK=32, 4 waves, 4x4 MFMA grid.
// ---------------------------------------------------------------------------
__device__ __forceinline__ void gemm128_core(const bf16* __restrict__ A,
                                             const bf16* __restrict__ Bt,
                                             int K, int k0, int k1, int mb, int nb,
                                             bf16 (*As)[32], bf16 (*Bs)[32],
                                             f32x4 (*acc)[4],
                                             int w, int l16, int quad, int lane)
{
    const int m0 = (w & 1) * 64, n0 = (w >> 1) * 64;
    const int srow = lane >> 2, scol = (lane & 3) * 8;

    for (int kt = k0; kt < k1; kt += 32) {
        __syncthreads();
        gload_lds16(&A [(size_t)(mb + w * 32 +      srow) * K + kt + scol], &As[w * 32     ][0]);
        gload_lds16(&A [(size_t)(mb + w * 32 + 16 + srow) * K + kt + scol], &As[w * 32 + 16][0]);
        gload_lds16(&Bt[(size_t)(nb + w * 32 +      srow) * K + kt + scol], &Bs[w * 32     ][0]);
        gload_lds16(&Bt[(size_t)(nb + w * 32 + 16 + srow) * K + kt + scol], &Bs[w * 32 + 16][0]);
        __syncthreads();

        bf16x8 af[4], bfr[4];
        #pragma unroll
        for (int t = 0; t < 4; ++t) af[t]  = *(const bf16x8*)&As[m0 + t * 16 + l16][quad * 8];
        #pragma unroll
        for (int u = 0; u < 4; ++u) bfr[u] = *(const bf16x8*)&Bs[n0 + u * 16 + l16][quad * 8];
        #pragma unroll
        for (int t = 0; t < 4; ++t)
            #pragma unroll
            for (int u = 0; u < 4; ++u)
                acc[t][u] = __builtin_amdgcn_mfma_f32_16x16x32_bf16(af[t], bfr[u], acc[t][u], 0, 0, 0);
    }
}

// Fused QKV projection with region routing (bounds are 128-multiples).
// (round-6-proven version: no rope epilogue)
__global__ __launch_bounds__(256) void gemm_qkv_kernel(const bf16* __restrict__ A,
                                                       const bf16* __restrict__ Wt,
                                                       bf16* __restrict__ qOut,
                                                       bf16* __restrict__ kOut,
                                                       bf16* __restrict__ vOut,
                                                       int M, int K)
{
    __shared__ __attribute__((aligned(16))) bf16 As[128][32];
    __shared__ __attribute__((aligned(16))) bf16 Bs[128][32];
    const int tid = threadIdx.x, w = tid >> 6, lane = tid & 63;
    const int l16 = lane & 15, quad = lane >> 4;
    const int mb = blockIdx.x * 128, nb = blockIdx.y * 128;
    const int m0 = (w & 1) * 64, n0 = (w >> 1) * 64;

    f32x4 acc[4][4] = {};
    gemm128_core(A, Wt, K, 0, K, mb, nb, As, Bs, acc, w, l16, quad, lane);

    #pragma unroll
    for (int t = 0; t < 4; ++t)
        #pragma unroll
        for (int u = 0; u < 4; ++u)
            #pragma unroll
            for (int r = 0; r < 4; ++r) {
                int row = mb + m0 + t * 16 + quad * 4 + r;
                int col = nb + n0 + u * 16 + l16;
                bf16 val = (bf16)acc[t][u][r];
                if (nb < 2048)       qOut[(size_t)row * HID + col] = val;
                else if (nb < 2560)  kOut[(size_t)row * KVD + (col - 2048)] = val;
                else                 vOut[(size_t)(col - 2560) * S_LEN + row] = val;
            }
}

// Wo GEMM, split-K=2, atomic f32 accumulate into pre-zeroed out.
__global__ __launch_bounds__(256) void gemm_wo_kernel(const bf16* __restrict__ A,
                                                      const bf16* __restrict__ Bt,
                                                      float* __restrict__ C,
                                                      int M, int N, int K)
{
    __shared__ __attribute__((aligned(16))) bf16 As[128][32];
    __shared__ __attribute__((aligned(16))) bf16 Bs[128][32];
    const int tid = threadIdx.x, w = tid >> 6, lane = tid & 63;
    const int l16 = lane & 15, quad = lane >> 4;
    const int mb = blockIdx.x * 128, nb = blockIdx.y * 128;
    const int m0 = (w & 1) * 64, n0 = (w >> 1) * 64;
    const int kh = K >> 1, k0 = blockIdx.z * kh;

    f32x4 acc[4][4] = {};
    gemm128_core(A, Bt, K, k0, k0 + kh, mb, nb, As, Bs, acc, w, l16, quad, lane);

    #pragma unroll
    for (int t = 0; t < 4; ++t)
        #pragma unroll
        for (int u = 0; u < 4; ++u)
            #pragma unroll
            for (int r = 0; r < 4; ++r) {
                int row = mb + m0 + t * 16 + quad * 4 + r;
                int col = nb + n0 + u * 16 + l16;
                unsafeAtomicAdd(&C[(size_t)row * N + col], acc[t][u][r]);
            }
}

// ---------------------------------------------------------------------------
// Merged in-place RoPE for q (16 heads) and k (4 heads); region-decoded grid.
// Thread owns pair (d, d+64) of one (s, head) row.
// ---------------------------------------------------------------------------
__global__ __launch_bounds__(256) void rope_kernel(bf16* __restrict__ qb,
                                                   bf16* __restrict__ kb,
                                                   const float* __restrict__ cosb,
                                                   const float* __restrict__ sinb)
{
    int idx = blockIdx.x * 256 + threadIdx.x;
    bf16* x; int s, rem, stride;
    if (idx < S_LEN * NH * 64) {
        x = qb; stride = HID;
        s = idx / (NH * 64); rem = idx % (NH * 64);
    } else {
        idx -= S_LEN * NH * 64;
        x = kb; stride = KVD;
        s = idx / (NKV * 64); rem = idx % (NKV * 64);
    }
    int h = rem >> 6, d = rem & 63;
    size_t base = (size_t)s * stride + h * 128 + d;
    float x0 = (float)x[base], x1 = (float)x[base + 64];
    float c0 = cosb[s * 128 + d], c1 = cosb[s * 128 + d + 64];
    float n0 = sinb[s * 128 + d], n1 = sinb[s * 128 + d + 64];
    x[base]      = (bf16)(x0 * c0 - x1 * n0);
    x[base + 64] = (bf16)(x1 * c1 + x0 * n1);
}

// ---------------------------------------------------------------------------
// Causal decay attention, j-split. Block = (qt, j-chunk of <=8 tiles, head).
// qt<8 (single chunk): final bf16 out. Else: f32 partial O + partial den.
// ---------------------------------------------------------------------------
__global__ __launch_bounds__(256) void attn_kernel(const bf16* __restrict__ q,
                                                   const bf16* __restrict__ k,
                                                   const bf16* __restrict__ vT,
                                                   const float* __restrict__ G,
                                                   bf16* __restrict__ out,
                                                   float* __restrict__ pO,
                                                   float* __restrict__ pden)
{
    int rem = blockIdx.x, qt = 0, cch = 0;
    #pragma unroll
    for (int g = 0; g < 4; ++g) {
        int sz = 8 * (g + 1);
        if (rem < sz) { qt = g * 8 + rem / (g + 1); cch = rem % (g + 1); break; }
        rem -= sz;
    }
    const int gg = qt >> 3, nc = gg + 1;
    const int jt0 = cch * 8, jt1 = min(qt + 1, jt0 + 8);

    const int h = blockIdx.y, kvh = h >> 2;
    const int qb = qt * 64;
    const int tid = threadIdx.x, w = tid >> 6, lane = tid & 63;
    const int l16 = lane & 15, quad = lane >> 4;

    __shared__ __attribute__((aligned(16))) bf16 Ks4[4][64][32];
    __shared__ __attribute__((aligned(16))) bf16 Vt4[2][128][32];
    __shared__ __attribute__((aligned(16))) bf16 Sb[4][16][68];

    bf16x8 qf[4];
    const int qrow = qb + w * 16 + l16;
    #pragma unroll
    for (int kc = 0; kc < 4; ++kc)
        qf[kc] = *(const bf16x8*)&q[(size_t)qrow * HID + h * HD + kc * 32 + quad * 8];

    const int irow = qb + w * 16 + quad * 4;
    float Gq[4];
    #pragma unroll
    for (int r = 0; r < 4; ++r) Gq[r] = G[kvh * S_LEN + irow + r];

    const int sr4 = lane >> 2, sc4 = (lane & 3) * 8;
    const int vkk = w >> 1, vdg = (w & 1) * 4;

    f32x4 acco[8] = {};
    float den[4] = {0.f, 0.f, 0.f, 0.f};

    for (int kt = jt0; kt < jt1; ++kt) {
        const int jb = kt * 64;
        __syncthreads();
        #pragma unroll
        for (int rg = 0; rg < 4; ++rg)
            gload_lds16(&k[(size_t)(jb + rg * 16 + sr4) * KVD + kvh * HD + w * 32 + sc4],
                        &Ks4[w][rg * 16][0]);
        #pragma unroll
        for (int it = 0; it < 4; ++it)
            gload_lds16(&vT[(size_t)(kvh * HD + (vdg + it) * 16 + sr4) * S_LEN + jb + vkk * 32 + sc4],
                        &Vt4[vkk][(vdg + it) * 16][0]);
        __syncthreads();

        f32x4 accs[4] = {};
        #pragma unroll
        for (int t = 0; t < 4; ++t)
            #pragma unroll
            for (int kc = 0; kc < 4; ++kc) {
                bf16x8 bfr = *(const bf16x8*)&Ks4[kc][t * 16 + l16][quad * 8];
                accs[t] = __builtin_amdgcn_mfma_f32_16x16x32_bf16(qf[kc], bfr, accs[t], 0, 0, 0);
            }

        const float Gt = G[kvh * S_LEN + jb];
        float sr[4];
        #pragma unroll
        for (int r = 0; r < 4; ++r) sr[r] = SCALE2 * __expf(Gq[r] - Gt);
        #pragma unroll
        for (int t = 0; t < 4; ++t) {
            int j = jb + t * 16 + l16;
            float colF = __expf(fminf(Gt - G[kvh * S_LEN + j], 85.f));
            #pragma unroll
            for (int r = 0; r < 4; ++r) {
                float d0 = accs[t][r];
                float sc = (j <= irow + r) ? d0 * d0 * sr[r] * colF : 0.f;
                den[r] += sc;
                Sb[w][quad * 4 + r][t * 16 + l16] = (bf16)sc;
            }
        }
        // no barrier: Sb[w] is wave-private

        #pragma unroll
        for (int kk = 0; kk < 2; ++kk) {
            bf16x8 af = *(const bf16x8*)&Sb[w][l16][kk * 32 + quad * 8];
            #pragma unroll
            for (int dt = 0; dt < 8; ++dt) {
                bf16x8 bfr = *(const bf16x8*)&Vt4[kk][dt * 16 + l16][quad * 8];
                acco[dt] = __builtin_amdgcn_mfma_f32_16x16x32_bf16(af, bfr, acco[dt], 0, 0, 0);
            }
        }
    }

    #pragma unroll
    for (int r = 0; r < 4; ++r) {
        #pragma unroll
        for (int off = 1; off < 16; off <<= 1) den[r] += __shfl_xor(den[r], off);
    }

    if (nc == 1) {
        float dinv[4];
        #pragma unroll
        for (int r = 0; r < 4; ++r) dinv[r] = 1.f / fmaxf(den[r], 1.f);
        #pragma unroll
        for (int dt = 0; dt < 8; ++dt)
            #pragma unroll
            for (int r = 0; r < 4; ++r)
                out[(size_t)(irow + r) * HID + h * HD + dt * 16 + l16] =
                    (bf16)(acco[dt][r] * dinv[r]);
    } else {
        const int slot = h * NCH + 4 * gg * (gg + 1) + (qt & 7) * (gg + 1) + cch;
        float* po = &pO[(size_t)slot * 8192];
        const int lr = w * 16 + quad * 4;
        #pragma unroll
        for (int dt = 0; dt < 8; ++dt)
            #pragma unroll
            for (int r = 0; r < 4; ++r)
                po[(lr + r) * 128 + dt * 16 + l16] = acco[dt][r];
        if (l16 == 0) {
            #pragma unroll
            for (int r = 0; r < 4; ++r) pden[slot * 64 + lr + r] = den[r];
        }
    }
}

// Combine partial chunks for qt >= 8. Grid: 16 heads x 24 qts.
__global__ __launch_bounds__(256) void attn_reduce_kernel(const float* __restrict__ pO,
                                                          const float* __restrict__ pden,
                                                          bf16* __restrict__ out)
{
    const int p = blockIdx.x;
    const int h = p / 24, qt = 8 + p % 24;
    const int gg = qt >> 3, nc = gg + 1;
    const int base = h * NCH + 4 * gg * (gg + 1) + (qt & 7) * (gg + 1);
    const int qb = qt * 64;
    const int tid = threadIdx.x;

    __shared__ float sden[64];
    if (tid < 64) {
        float s = 0.f;
        for (int c = 0; c < nc; ++c) s += pden[(base + c) * 64 + tid];
        sden[tid] = 1.f / fmaxf(s, 1.f);
    }
    __syncthreads();

    #pragma unroll
    for (int i = 0; i < 8; ++i) {
        int e = i * 1024 + tid * 4;
        float4 s = make_float4(0.f, 0.f, 0.f, 0.f);
        for (int c = 0; c < nc; ++c) {
            float4 v = *(const float4*)&pO[(size_t)(base + c) * 8192 + e];
            s.x += v.x; s.y += v.y; s.z += v.z; s.w += v.w;
        }
        int lr = e >> 7, col = e & 127;
        float di = sden[lr];
        bf16* o = &out[(size_t)(qb + lr) * HID + h * HD + col];
        o[0] = (bf16)(s.x * di); o[1] = (bf16)(s.y * di);
        o[2] = (bf16)(s.z * di); o[3] = (bf16)(s.w * di);
    }
}

// ---------------------------------------------------------------------------
extern "C" void kernel_launch(void* const* d_in, const int* in_sizes, int n_in,
                              void* d_out, int out_size, void* d_ws, size_t ws_size,
                              hipStream_t stream)
{
    const float* hs   = (const float*)d_in[0];
    const float* cosb = (const float*)d_in[1];
    const float* sinb = (const float*)d_in[2];
    const float* Wq   = (const float*)d_in[3];
    const float* Wk   = (const float*)d_in[4];
    const float* Wv   = (const float*)d_in[5];
    const float* Wg   = (const float*)d_in[6];
    const float* Wo   = (const float*)d_in[7];
    float* out = (float*)d_out;

    char* p = (char*)d_ws;
    bf16*  qbuf  = (bf16*)p;  p += (size_t)S_LEN * HID * 2;    // 8 MB
    bf16*  kbuf  = (bf16*)p;  p += (size_t)S_LEN * KVD * 2;    // 2 MB
    bf16*  vT    = (bf16*)p;  p += (size_t)S_LEN * KVD * 2;    // 2 MB ([KVD][S])
    bf16*  abuf  = (bf16*)p;  p += (size_t)S_LEN * HID * 2;    // 8 MB
    bf16*  hsb   = (bf16*)p;  p += (size_t)S_LEN * HID * 2;    // 8 MB
    bf16*  WcatT = (bf16*)p;  p += (size_t)NQKV * HID * 2;     // 12 MB
    bf16*  WoT   = (bf16*)p;  p += (size_t)HID * HID * 2;      // 8 MB
    float* graw  = (float*)p; p += (size_t)NKV * S_LEN * 4;
    float* G     = (float*)p; p += (size_t)NKV * S_LEN * 4;
    float* pO    = (float*)p; p += (size_t)NH * NCH * 8192 * 4; // 41.9 MB
    float* pden  = (float*)p; p += (size_t)NH * NCH * 64 * 4;   // 0.33 MB

    // 1: fused pre-pass (cvt + 4 transposes + zero-out + gate projection)
    prep_kernel<<<7168, 256, 0, stream>>>(hs, Wq, Wk, Wv, Wo, Wg,
                                          hsb, WcatT, WoT, graw, out);
    // 2: gate cumsum
    cumsum_kernel<<<NKV, 256, 0, stream>>>(graw, G);
    // 3: fused QKV projection (V written transposed)
    gemm_qkv_kernel<<<dim3(16, 24), 256, 0, stream>>>(hsb, WcatT, qbuf, kbuf, vT, S_LEN, HID);
    // 4: merged RoPE for q and k
    rope_kernel<<<(S_LEN * NH * 64 + S_LEN * NKV * 64) / 256, 256, 0, stream>>>(qbuf, kbuf, cosb, sinb);
    // 5: j-split attention
    attn_kernel<<<dim3(NCH, NH), 256, 0, stream>>>(qbuf, kbuf, vT, G, abuf, pO, pden);
    // 6: combine
    attn_reduce_kernel<<<NH * 24, 256, 0, stream>>>(pO, pden, abuf);
    // 7: output projection (split-K=2, atomic into zeroed out)
    gemm_wo_kernel<<<dim3(16, 16, 2), 256, 0, stream>>>(abuf, WoT, out, S_LEN, HID, HID);
}